// Round 18
// baseline (187.995 us; speedup 1.0000x reference)
//
#include <hip/hip_runtime.h>
#include <math.h>

constexpr int H = 64;

typedef __attribute__((ext_vector_type(8))) short bf16x8;
typedef __attribute__((ext_vector_type(4))) float f32x4;
typedef __attribute__((ext_vector_type(2))) float f32x2;
typedef unsigned long long u64;

__device__ inline unsigned short f2bf(float f) {
  union { float f; unsigned int u; } c; c.f = f;
  unsigned int u = c.u;
  return (unsigned short)((u + 0x7FFF + ((u >> 16) & 1)) >> 16);  // RNE
}
__device__ inline float bf2f(unsigned int s) {
  union { unsigned int u; float f; } c; c.u = s << 16;
  return c.f;
}
// fp8 e4m3 via HW cvt (encode+decode on same chip -> self-consistent format)
__device__ inline unsigned char f2fp8(float f) {
  return (unsigned char)(__builtin_amdgcn_cvt_pk_fp8_f32(f, f, 0, false) & 0xFF);
}

// ---- prep: zero hsumP+bcur2, transpose+bf16 weights (one kernel) ----
__global__ void k_prep(int* __restrict__ hist, float* __restrict__ hsumP,
                       int* __restrict__ bcur2,
                       const float* __restrict__ Wmsg, const float* __restrict__ Wupd,
                       unsigned short* __restrict__ WmT, unsigned short* __restrict__ WuT,
                       int n) {
  int t = blockIdx.x * blockDim.x + threadIdx.x;
  if (t < n) hist[t] = 0;
  if (t < 512) hsumP[t] = 0.f;
  if (t < 64) bcur2[t] = 0;
  int u = t - n;
  if (u >= 0 && u < 3 * 12288) {
    int l = u / 12288, rem = u % 12288;
    if (rem < 4096) {
      int j = rem >> 6, k = rem & 63;
      WmT[l * 4096 + rem] = f2bf(Wmsg[(size_t)l * 66 * 64 + k * 64 + j]);
    } else {
      int r2 = rem - 4096;
      int j = r2 >> 7, k = r2 & 127;
      WuT[l * 8192 + r2] = f2bf(Wupd[(size_t)l * 128 * 64 + k * 64 + j]);
    }
  }
}

// ---- fallback-path CSR build (N > 65536 only) ----
__global__ void k_hist(const int* __restrict__ dst, int* __restrict__ hist, int E) {
  int e = blockIdx.x * blockDim.x + threadIdx.x;
  if (e < E) atomicAdd(&hist[dst[e]], 1);
}

__global__ void k_scan1(const int* __restrict__ hist, int* __restrict__ bsum, int n) {
  __shared__ int sred[256];
  int tid = threadIdx.x;
  int base = blockIdx.x * 1024 + tid * 4;
  int s = 0;
#pragma unroll
  for (int k = 0; k < 4; ++k) { int i = base + k; if (i < n) s += hist[i]; }
  sred[tid] = s;
  __syncthreads();
  for (int d = 128; d > 0; d >>= 1) {
    if (tid < d) sred[tid] += sred[tid + d];
    __syncthreads();
  }
  if (tid == 0) bsum[blockIdx.x] = sred[0];
}

__global__ void k_scan2(int* __restrict__ bsum, int nb) {
  __shared__ int sd[1024];
  int tid = threadIdx.x;
  int v = (tid < nb) ? bsum[tid] : 0;
  sd[tid] = v;
  __syncthreads();
  for (int d = 1; d < 1024; d <<= 1) {
    int t = (tid >= d) ? sd[tid - d] : 0;
    __syncthreads();
    sd[tid] += t;
    __syncthreads();
  }
  if (tid < nb) bsum[tid] = sd[tid] - v;
}

__global__ void k_scan3(const int* __restrict__ hist, const int* __restrict__ bsum,
                        int* __restrict__ row_ptr, int* __restrict__ pos, int n) {
  __shared__ int sth[256];
  int tid = threadIdx.x;
  int base = blockIdx.x * 1024 + tid * 4;
  int v[4]; int s = 0;
#pragma unroll
  for (int k = 0; k < 4; ++k) { int i = base + k; v[k] = (i < n) ? hist[i] : 0; s += v[k]; }
  sth[tid] = s;
  __syncthreads();
  for (int d = 1; d < 256; d <<= 1) {
    int t = (tid >= d) ? sth[tid - d] : 0;
    __syncthreads();
    sth[tid] += t;
    __syncthreads();
  }
  int run = bsum[blockIdx.x] + sth[tid] - s;
  if (blockIdx.x == 0 && tid == 0) row_ptr[0] = 0;
#pragma unroll
  for (int k = 0; k < 4; ++k) {
    int i = base + k;
    if (i < n) {
      pos[i] = run;
      run += v[k];
      row_ptr[i + 1] = run;
    }
  }
}

__global__ void k_scatter(const int* __restrict__ src, const int* __restrict__ dst,
                          const float* __restrict__ ea, int* __restrict__ pos,
                          u64* __restrict__ erec, int E) {
  int e = blockIdx.x * blockDim.x + threadIdx.x;
  if (e < E) {
    int d = dst[e];
    int p = atomicAdd(&pos[d], 1);
    u64 lo = f2bf(ea[2 * e]);
    u64 hi = f2bf(ea[2 * e + 1]);
    erec[p] = (u64)(unsigned int)src[e] | ((lo | (hi << 16)) << 32);
  }
}

// ---- k_part: block-local bucket sort (2048 edges/block); NO global hist ----
__global__ void k_part(const int* __restrict__ src, const int* __restrict__ dst,
                       const float2* __restrict__ ea2,
                       int* __restrict__ bcur2,
                       u64* __restrict__ staged, int E, int B, int C) {
  __shared__ u64 srt[2048];                   // 16 KB
  __shared__ int cnt[64], offs[64], gbase[64];
  int tid = threadIdx.x;
  int base = blockIdx.x * 2048;
  if (tid < 64) cnt[tid] = 0;
  __syncthreads();
  u64 rec_[8]; int bk_[8], rk_[8];
#pragma unroll
  for (int k = 0; k < 8; ++k) {
    int e = base + k * 256 + tid;
    if (e < E) {
      int d = dst[e];
      int bk = d >> 10;
      float2 eav = ea2[e];
      unsigned int eap = (unsigned int)f2bf(eav.x) | ((unsigned int)f2bf(eav.y) << 16);
      rec_[k] = (u64)(unsigned int)(src[e] & 0xFFFF)
              | ((u64)(unsigned int)(d & 1023) << 16)
              | ((u64)(unsigned int)bk << 26)
              | ((u64)eap << 32);
      bk_[k] = bk;
      rk_[k] = atomicAdd(&cnt[bk], 1);
    } else bk_[k] = -1;
  }
  __syncthreads();
  if (tid == 0) {
    int run = 0;
    for (int b = 0; b < B; ++b) { offs[b] = run; run += cnt[b]; }
  }
  __syncthreads();
#pragma unroll
  for (int k = 0; k < 8; ++k)
    if (bk_[k] >= 0) srt[offs[bk_[k]] + rk_[k]] = rec_[k];
  __syncthreads();
  if (tid < B && cnt[tid] > 0) gbase[tid] = atomicAdd(&bcur2[tid], cnt[tid]);
  __syncthreads();
  int total = (base + 2048 <= E) ? 2048 : (E > base ? E - base : 0);
  for (int i = tid; i < total; i += 256) {
    u64 r = srt[i];
    int bk = (int)((r >> 26) & 63u);
    staged[(size_t)bk * C + gbase[bk] + (i - offs[bk])] = r;  // full-line appends
  }
}

// ---- k_place: per-bucket histogram + scan -> row_ptr; then place records ----
__global__ void k_place(const u64* __restrict__ staged, const int* __restrict__ bcur2,
                        int* __restrict__ row_ptr, u64* __restrict__ erec,
                        int N_, int C, int B) {
  __shared__ int cnt2[1024];
  __shared__ int rloc[1024];
  __shared__ int sbase;
  int b = blockIdx.x;
  int nd0 = b << 10;
  int nn = min(nd0 + 1024, N_) - nd0;
  int tid = threadIdx.x;  // 1024 threads
  cnt2[tid] = 0;
  if (tid == 0) {
    int s = 0;
    for (int i = 0; i < b; ++i) s += bcur2[i];
    sbase = s;
  }
  __syncthreads();
  int count = bcur2[b];
  const u64* sb = staged + (size_t)b * C;
  for (int i = tid; i < count; i += 1024) {
    int dl = (int)((sb[i] >> 16) & 1023u);
    atomicAdd(&cnt2[dl], 1);
  }
  __syncthreads();
  int v = cnt2[tid];
  rloc[tid] = v;
  __syncthreads();
  for (int d = 1; d < 1024; d <<= 1) {
    int t = (tid >= d) ? rloc[tid - d] : 0;
    __syncthreads();
    rloc[tid] += t;
    __syncthreads();
  }
  int myrp = sbase + rloc[tid] - v;
  __syncthreads();
  rloc[tid] = myrp;
  cnt2[tid] = 0;
  if (tid < nn) row_ptr[nd0 + tid] = myrp;
  if (b == B - 1 && tid == 0) row_ptr[N_] = sbase + count;
  __syncthreads();
  for (int i = tid; i < count; i += 1024) {
    u64 r = sb[i];
    int dl = (int)((r >> 16) & 1023u);
    int p = rloc[dl] + atomicAdd(&cnt2[dl], 1);
    erec[p] = (r & 0xFFFFull) | ((r >> 32) << 32);
  }
}

// ---- fused input projection + gemm0 ----
__global__ void k_inproj_gemm(const float* __restrict__ x, const float* __restrict__ Win,
                              const float* __restrict__ bin,
                              const unsigned short* __restrict__ wmt,
                              unsigned short* __restrict__ hb,
                              unsigned char* __restrict__ g, int n) {
  int lane = threadIdx.x & 63;
  int wv = blockIdx.x * (blockDim.x >> 6) + (threadIdx.x >> 6);
  int v0 = wv * 16;
  if (v0 >= n) return;
  int r16 = lane & 15, hi = lane >> 4;
  int row = v0 + r16;
  float x0 = 0.f, x1 = 0.f;
  if (row < n) { x0 = x[2 * row]; x1 = x[2 * row + 1]; }
  union { bf16x8 v; unsigned short u[8]; } af[2];
#pragma unroll
  for (int s = 0; s < 2; ++s)
#pragma unroll
    for (int t = 0; t < 8; ++t) {
      int j = s * 32 + hi * 8 + t;
      af[s].u[t] = f2bf(fmaf(x0, Win[j], fmaf(x1, Win[64 + j], bin[j])));
    }
  if (row < n) {
    *(bf16x8*)(hb + (size_t)row * H + hi * 8)      = af[0].v;
    *(bf16x8*)(hb + (size_t)row * H + 32 + hi * 8) = af[1].v;
  }
  bf16x8 bfr[2][4];
#pragma unroll
  for (int ks = 0; ks < 2; ++ks)
#pragma unroll
    for (int jt = 0; jt < 4; ++jt)
      bfr[ks][jt] = *(const bf16x8*)(wmt + (jt * 16 + r16) * 64 + ks * 32 + hi * 8);
  f32x4 acc[4] = {};
#pragma unroll
  for (int ks = 0; ks < 2; ++ks)
#pragma unroll
    for (int jt = 0; jt < 4; ++jt)
      acc[jt] = __builtin_amdgcn_mfma_f32_16x16x32_bf16(af[ks].v, bfr[ks][jt], acc[jt], 0, 0, 0);
#pragma unroll
  for (int jt = 0; jt < 4; ++jt) {
    int col = jt * 16 + r16;
#pragma unroll
    for (int r = 0; r < 4; ++r) {
      int orow = v0 + hi * 4 + r;
      if (orow < n) g[(size_t)orow * H + col] = f2fp8(acc[jt][r]);
    }
  }
}

// ---- per-chain accumulate: 8 fp8 feats via packed cvt (2 f32/instr) ----
__device__ inline void acc8(float* a, uint2 gw, float e0, float e1,
                            const float4 waL, const float4 waH,
                            const float4 wbL, const float4 wbH,
                            const float4 bL, const float4 bH) {
  f32x2 g01 = __builtin_amdgcn_cvt_pk_f32_fp8(gw.x, false);
  f32x2 g23 = __builtin_amdgcn_cvt_pk_f32_fp8(gw.x, true);
  f32x2 g45 = __builtin_amdgcn_cvt_pk_f32_fp8(gw.y, false);
  f32x2 g67 = __builtin_amdgcn_cvt_pk_f32_fp8(gw.y, true);
  a[0] += fmaxf(fmaf(e0, waL.x, fmaf(e1, wbL.x, g01.x + bL.x)), 0.f);
  a[1] += fmaxf(fmaf(e0, waL.y, fmaf(e1, wbL.y, g01.y + bL.y)), 0.f);
  a[2] += fmaxf(fmaf(e0, waL.z, fmaf(e1, wbL.z, g23.x + bL.z)), 0.f);
  a[3] += fmaxf(fmaf(e0, waL.w, fmaf(e1, wbL.w, g23.y + bL.w)), 0.f);
  a[4] += fmaxf(fmaf(e0, waH.x, fmaf(e1, wbH.x, g45.x + bH.x)), 0.f);
  a[5] += fmaxf(fmaf(e0, waH.y, fmaf(e1, wbH.y, g45.y + bH.y)), 0.f);
  a[6] += fmaxf(fmaf(e0, waH.z, fmaf(e1, wbH.z, g67.x + bH.z)), 0.f);
  a[7] += fmaxf(fmaf(e0, waH.w, fmaf(e1, wbH.w, g67.y + bH.w)), 0.f);
}

// ---- fused layer: 32 nodes/block; 8-wide gather chains in phase 1 ----
__global__ void k_layer(const unsigned char* __restrict__ g_in,
                        const int* __restrict__ row_ptr, const u64* __restrict__ erec,
                        const float* __restrict__ Wm2, const float* __restrict__ bm,
                        unsigned short* __restrict__ hb,
                        const unsigned short* __restrict__ wut,
                        const float* __restrict__ bu,
                        const unsigned short* __restrict__ wmt_next, // null on last layer
                        unsigned char* __restrict__ g_out,
                        float* __restrict__ hout,                    // non-null on last layer
                        const float* __restrict__ Wn, const float* __restrict__ bn,
                        float* __restrict__ probs, float* __restrict__ hsumP,
                        int n) {
  __shared__ __align__(16) unsigned short aggL[32][72];
  __shared__ __align__(16) unsigned short hstage[2][16][72];
  __shared__ float shsum[64];
  int v0 = blockIdx.x * 32;

  // ---- phase 1: 32 groups aggregate 32 nodes into aggL ----
  {
    int gid = threadIdx.x >> 3, r = threadIdx.x & 7;
    int j0 = r * 8;
    float4 waL = *(const float4*)(Wm2 + j0);
    float4 waH = *(const float4*)(Wm2 + j0 + 4);
    float4 wbL = *(const float4*)(Wm2 + 64 + j0);
    float4 wbH = *(const float4*)(Wm2 + 64 + j0 + 4);
    float4 bL  = *(const float4*)(bm + j0);
    float4 bH  = *(const float4*)(bm + j0 + 4);
    int v = v0 + gid;
    uint4 o = make_uint4(0, 0, 0, 0);
    if (v < n) {
      int beg = row_ptr[v], end = row_ptr[v + 1];
      float a[8] = {0.f, 0.f, 0.f, 0.f, 0.f, 0.f, 0.f, 0.f};
      int i = beg;
      for (; i + 7 < end; i += 8) {  // 8 independent gather chains
        u64 r0 = erec[i],     r1 = erec[i + 1], r2 = erec[i + 2], r3 = erec[i + 3];
        u64 r4 = erec[i + 4], r5 = erec[i + 5], r6 = erec[i + 6], r7 = erec[i + 7];
        uint2 g0 = *(const uint2*)(g_in + (size_t)(unsigned int)r0 * H + j0);
        uint2 g1 = *(const uint2*)(g_in + (size_t)(unsigned int)r1 * H + j0);
        uint2 g2 = *(const uint2*)(g_in + (size_t)(unsigned int)r2 * H + j0);
        uint2 g3 = *(const uint2*)(g_in + (size_t)(unsigned int)r3 * H + j0);
        uint2 g4 = *(const uint2*)(g_in + (size_t)(unsigned int)r4 * H + j0);
        uint2 g5 = *(const uint2*)(g_in + (size_t)(unsigned int)r5 * H + j0);
        uint2 g6 = *(const uint2*)(g_in + (size_t)(unsigned int)r6 * H + j0);
        uint2 g7 = *(const uint2*)(g_in + (size_t)(unsigned int)r7 * H + j0);
        unsigned int e0 = (unsigned int)(r0 >> 32), e1 = (unsigned int)(r1 >> 32);
        unsigned int e2 = (unsigned int)(r2 >> 32), e3 = (unsigned int)(r3 >> 32);
        unsigned int e4 = (unsigned int)(r4 >> 32), e5 = (unsigned int)(r5 >> 32);
        unsigned int e6 = (unsigned int)(r6 >> 32), e7 = (unsigned int)(r7 >> 32);
        acc8(a, g0, bf2f(e0 & 0xffffu), bf2f(e0 >> 16), waL, waH, wbL, wbH, bL, bH);
        acc8(a, g1, bf2f(e1 & 0xffffu), bf2f(e1 >> 16), waL, waH, wbL, wbH, bL, bH);
        acc8(a, g2, bf2f(e2 & 0xffffu), bf2f(e2 >> 16), waL, waH, wbL, wbH, bL, bH);
        acc8(a, g3, bf2f(e3 & 0xffffu), bf2f(e3 >> 16), waL, waH, wbL, wbH, bL, bH);
        acc8(a, g4, bf2f(e4 & 0xffffu), bf2f(e4 >> 16), waL, waH, wbL, wbH, bL, bH);
        acc8(a, g5, bf2f(e5 & 0xffffu), bf2f(e5 >> 16), waL, waH, wbL, wbH, bL, bH);
        acc8(a, g6, bf2f(e6 & 0xffffu), bf2f(e6 >> 16), waL, waH, wbL, wbH, bL, bH);
        acc8(a, g7, bf2f(e7 & 0xffffu), bf2f(e7 >> 16), waL, waH, wbL, wbH, bL, bH);
      }
      for (; i + 3 < end; i += 4) {  // 4-wide mid loop
        u64 r0 = erec[i], r1 = erec[i + 1], r2 = erec[i + 2], r3 = erec[i + 3];
        uint2 g0 = *(const uint2*)(g_in + (size_t)(unsigned int)r0 * H + j0);
        uint2 g1 = *(const uint2*)(g_in + (size_t)(unsigned int)r1 * H + j0);
        uint2 g2 = *(const uint2*)(g_in + (size_t)(unsigned int)r2 * H + j0);
        uint2 g3 = *(const uint2*)(g_in + (size_t)(unsigned int)r3 * H + j0);
        unsigned int e0 = (unsigned int)(r0 >> 32), e1 = (unsigned int)(r1 >> 32);
        unsigned int e2 = (unsigned int)(r2 >> 32), e3 = (unsigned int)(r3 >> 32);
        acc8(a, g0, bf2f(e0 & 0xffffu), bf2f(e0 >> 16), waL, waH, wbL, wbH, bL, bH);
        acc8(a, g1, bf2f(e1 & 0xffffu), bf2f(e1 >> 16), waL, waH, wbL, wbH, bL, bH);
        acc8(a, g2, bf2f(e2 & 0xffffu), bf2f(e2 >> 16), waL, waH, wbL, wbH, bL, bH);
        acc8(a, g3, bf2f(e3 & 0xffffu), bf2f(e3 >> 16), waL, waH, wbL, wbH, bL, bH);
      }
      for (; i < end; ++i) {
        u64 r0 = erec[i];
        uint2 g0 = *(const uint2*)(g_in + (size_t)(unsigned int)r0 * H + j0);
        unsigned int e0 = (unsigned int)(r0 >> 32);
        acc8(a, g0, bf2f(e0 & 0xffffu), bf2f(e0 >> 16), waL, waH, wbL, wbH, bL, bH);
      }
      float inv = 1.f / fmaxf((float)(end - beg), 1.f);
      o.x = (unsigned int)f2bf(a[0] * inv) | ((unsigned int)f2bf(a[1] * inv) << 16);
      o.y = (unsigned int)f2bf(a[2] * inv) | ((unsigned int)f2bf(a[3] * inv) << 16);
      o.z = (unsigned int)f2bf(a[4] * inv) | ((unsigned int)f2bf(a[5] * inv) << 16);
      o.w = (unsigned int)f2bf(a[6] * inv) | ((unsigned int)f2bf(a[7] * inv) << 16);
    }
    *(uint4*)(&aggL[gid][j0]) = o;
  }
  __syncthreads();

  // ---- phase 2: waves 0,1 do the update MFMA for rows v0..v0+31 ----
  int lane = threadIdx.x & 63;
  int w = threadIdx.x >> 6;
  bool mw = (w < 2);
  int wv0 = v0 + w * 16;
  bool act = mw && (wv0 < n);
  int r16 = lane & 15, hi = lane >> 4;
  if (hout && threadIdx.x < 64) shsum[threadIdx.x] = 0.f;
  bf16x8 bfr[4][4];
#pragma unroll
  for (int ks = 0; ks < 4; ++ks)
#pragma unroll
    for (int jt = 0; jt < 4; ++jt)
      bfr[ks][jt] = *(const bf16x8*)(wut + (jt * 16 + r16) * 128 + ks * 32 + hi * 8);
  f32x4 acc[4];
#pragma unroll
  for (int jt = 0; jt < 4; ++jt) {
    float b = bu[jt * 16 + r16];
    acc[jt] = (f32x4){b, b, b, b};
  }
  bf16x8 afr[4];
  int row = wv0 + r16;
  if (act && row < n) {
    const unsigned short* hrow = hb + (size_t)row * H + hi * 8;
    afr[0] = *(const bf16x8*)(hrow);
    afr[1] = *(const bf16x8*)(hrow + 32);
  } else {
    afr[0] = afr[1] = (bf16x8){0,0,0,0,0,0,0,0};
  }
  if (mw) {
    int lw = w * 16 + r16;
    afr[2] = *(const bf16x8*)(&aggL[lw][hi * 8]);
    afr[3] = *(const bf16x8*)(&aggL[lw][32 + hi * 8]);
  } else {
    afr[2] = afr[3] = (bf16x8){0,0,0,0,0,0,0,0};
  }
#pragma unroll
  for (int ks = 0; ks < 4; ++ks)
#pragma unroll
    for (int jt = 0; jt < 4; ++jt)
      acc[jt] = __builtin_amdgcn_mfma_f32_16x16x32_bf16(afr[ks], bfr[ks][jt], acc[jt], 0, 0, 0);
  float ov[4][4];
  unsigned short ob[4][4];
#pragma unroll
  for (int jt = 0; jt < 4; ++jt) {
    int col = jt * 16 + r16;
#pragma unroll
    for (int r = 0; r < 4; ++r) {
      int orow = wv0 + hi * 4 + r;
      bool ok = act && orow < n;
      float o = fmaxf(acc[jt][r], 0.f);
      ov[jt][r] = ok ? o : 0.f;
      ob[jt][r] = f2bf(ov[jt][r]);
      if (ok) {
        hb[(size_t)orow * H + col] = ob[jt][r];
        if (hout) hout[(size_t)orow * H + col] = o;
      }
    }
  }
  if (wmt_next) {
    if (mw) {
#pragma unroll
      for (int jt = 0; jt < 4; ++jt)
#pragma unroll
        for (int r = 0; r < 4; ++r)
          hstage[w][hi * 4 + r][jt * 16 + r16] = ob[jt][r];
    }
    __syncthreads();
    if (mw) {
      bf16x8 af2[2];
      af2[0] = *(const bf16x8*)(&hstage[w][r16][hi * 8]);
      af2[1] = *(const bf16x8*)(&hstage[w][r16][32 + hi * 8]);
      bf16x8 bf2r[2][4];
#pragma unroll
      for (int ks = 0; ks < 2; ++ks)
#pragma unroll
        for (int jt = 0; jt < 4; ++jt)
          bf2r[ks][jt] = *(const bf16x8*)(wmt_next + (jt * 16 + r16) * 64 + ks * 32 + hi * 8);
      f32x4 acc2[4] = {};
#pragma unroll
      for (int ks = 0; ks < 2; ++ks)
#pragma unroll
        for (int jt = 0; jt < 4; ++jt)
          acc2[jt] = __builtin_amdgcn_mfma_f32_16x16x32_bf16(af2[ks], bf2r[ks][jt], acc2[jt], 0, 0, 0);
#pragma unroll
      for (int jt = 0; jt < 4; ++jt) {
        int col = jt * 16 + r16;
#pragma unroll
        for (int r = 0; r < 4; ++r) {
          int orow = wv0 + hi * 4 + r;
          if (act && orow < n) g_out[(size_t)orow * H + col] = f2fp8(acc2[jt][r]);
        }
      }
    }
  } else {
    float bn0 = bn[0];
    float lg[4] = {0.f, 0.f, 0.f, 0.f};
#pragma unroll
    for (int jt = 0; jt < 4; ++jt) {
      float wn = Wn[jt * 16 + r16];
#pragma unroll
      for (int r = 0; r < 4; ++r) lg[r] = fmaf(ov[jt][r], wn, lg[r]);
    }
#pragma unroll
    for (int d = 1; d < 16; d <<= 1) {
#pragma unroll
      for (int r = 0; r < 4; ++r) lg[r] += __shfl_xor(lg[r], d);
    }
    if (r16 == 0 && act) {
#pragma unroll
      for (int r = 0; r < 4; ++r) {
        int orow = wv0 + hi * 4 + r;
        if (orow < n) probs[orow] = 1.f / (1.f + expf(-(lg[r] + bn0)));
      }
    }
    __syncthreads();
#pragma unroll
    for (int jt = 0; jt < 4; ++jt) {
      float s = ov[jt][0] + ov[jt][1] + ov[jt][2] + ov[jt][3];
      s += __shfl_xor(s, 16); s += __shfl_xor(s, 32);
      if (hi == 0) atomicAdd(&shsum[jt * 16 + r16], s);
    }
    __syncthreads();
    if (threadIdx.x < 64)
      atomicAdd(&hsumP[((blockIdx.x & 7) << 6) + threadIdx.x], shsum[threadIdx.x]);
  }
}

// ---- global mean + 2-layer head (tiny) ----
__global__ void k_final(const float* __restrict__ hsumP,
                        const float* __restrict__ W1, const float* __restrict__ b1,
                        const float* __restrict__ W2, const float* __restrict__ b2,
                        float* __restrict__ out4, float n_nodes) {
  __shared__ float hmean[64];
  __shared__ float z1[32];
  int tid = threadIdx.x;
  if (tid < 64) {
    float s = 0.f;
#pragma unroll
    for (int b = 0; b < 8; ++b) s += hsumP[b * 64 + tid];
    hmean[tid] = s / n_nodes;
  }
  __syncthreads();
  if (tid < 32) {
    float a = b1[tid];
    for (int k = 0; k < 64; ++k) a = fmaf(hmean[k], W1[k * 32 + tid], a);
    z1[tid] = fmaxf(a, 0.f);
  }
  __syncthreads();
  if (tid < 4) {
    float a = b2[tid];
    for (int k = 0; k < 32; ++k) a = fmaf(z1[k], W2[k * 4 + tid], a);
    out4[tid] = a;
  }
}

extern "C" void kernel_launch(void* const* d_in, const int* in_sizes, int n_in,
                              void* d_out, int out_size, void* d_ws, size_t ws_size,
                              hipStream_t stream) {
  const float* x    = (const float*)d_in[0];
  const int*   ei   = (const int*)d_in[1];
  const float* ea   = (const float*)d_in[2];
  const float* Win  = (const float*)d_in[3];
  const float* bin  = (const float*)d_in[4];
  const float* Wmsg = (const float*)d_in[5];
  const float* bmsg = (const float*)d_in[6];
  const float* Wupd = (const float*)d_in[7];
  const float* bupd = (const float*)d_in[8];
  const float* Wn   = (const float*)d_in[9];
  const float* bn   = (const float*)d_in[10];
  const float* W1   = (const float*)d_in[13];
  const float* b1   = (const float*)d_in[14];
  const float* W2   = (const float*)d_in[15];
  const float* b2   = (const float*)d_in[16];

  const int N = in_sizes[0] / 2;
  const int E = in_sizes[1] / 2;
  const int* src = ei;
  const int* dst = ei + E;

  const int B = (N + 1023) >> 10;            // dst-buckets of 1024 nodes
  const int C = (2 * (E / (B > 0 ? B : 1)) + 2048 + 255) & ~255;  // per-bucket staging cap

  char* ws = (char*)d_ws;
  size_t off = 0;
  auto alloc = [&](size_t bytes) {
    void* p = ws + off;
    off = (off + bytes + 255) & ~(size_t)255;
    return p;
  };
  int*   hist  = (int*)  alloc((size_t)N * 4);
  int*   rptr  = (int*)  alloc((size_t)(N + 1) * 4);
  int*   pos   = (int*)  alloc((size_t)N * 4);
  int*   bsum  = (int*)  alloc((size_t)1024 * 4);
  int*   bcur2 = (int*)  alloc((size_t)64 * 4);
  u64*   staged = (u64*) alloc((size_t)(B <= 64 ? 64 : 0) * C * 8 + 8);
  u64*   erec  = (u64*)  alloc((size_t)E * 8);
  unsigned short* hb   = (unsigned short*)alloc((size_t)N * H * 2);
  unsigned char*  gA   = (unsigned char*) alloc((size_t)N * H);   // fp8 ping
  unsigned char*  gB   = (unsigned char*) alloc((size_t)N * H);   // fp8 pong
  unsigned short* WmT  = (unsigned short*)alloc((size_t)3 * 64 * 64 * 2);
  unsigned short* WuT  = (unsigned short*)alloc((size_t)3 * 64 * 128 * 2);
  float* hsumP = (float*)alloc(8 * 64 * 4);
  (void)ws_size;

  float* probs = (float*)d_out;          // [N]
  float* out4  = probs + N;              // [4]
  float* h     = out4 + 4;               // [N, 64] fp32 final embeddings

  int eb = (E + 255) / 256;
  int sb = (N + 1023) / 1024;
  k_prep<<<(N + 3 * 12288 + 255) / 256, 256, 0, stream>>>(hist, hsumP, bcur2,
                                                          Wmsg, Wupd, WmT, WuT, N);
  if (B <= 64) {
    k_part<<<(E + 2047) / 2048, 256, 0, stream>>>(src, dst, (const float2*)ea,
                                                  bcur2, staged, E, B, C);
    k_place<<<B, 1024, 0, stream>>>(staged, bcur2, rptr, erec, N, C, B);
  } else {
    k_hist<<<eb, 256, 0, stream>>>(dst, hist, E);
    k_scan1<<<sb, 256, 0, stream>>>(hist, bsum, N);
    k_scan2<<<1, 1024, 0, stream>>>(bsum, sb);
    k_scan3<<<sb, 256, 0, stream>>>(hist, bsum, rptr, pos, N);
    k_scatter<<<eb, 256, 0, stream>>>(src, dst, ea, pos, erec, E);
  }

  int tiles = (N + 15) / 16;
  int mb = (tiles + 3) / 4;
  k_inproj_gemm<<<mb, 256, 0, stream>>>(x, Win, bin, WmT, hb, gA, N);

  int lb = (N + 31) / 32;     // fused layer: 32 nodes/block, 1 node per 8-lane group
  for (int l = 0; l < 3; ++l) {
    const unsigned char* gin = (l & 1) ? gB : gA;
    unsigned char* gout      = (l & 1) ? gA : gB;
    k_layer<<<lb, 256, 0, stream>>>(gin, rptr, erec,
                                    Wmsg + (size_t)l * 66 * 64 + 64 * 64,
                                    bmsg + (size_t)l * 64,
                                    hb, WuT + (size_t)l * 64 * 128,
                                    bupd + (size_t)l * 64,
                                    (l < 2) ? (WmT + (size_t)(l + 1) * 64 * 64) : nullptr,
                                    gout,
                                    (l == 2) ? h : nullptr,
                                    Wn, bn, probs, hsumP, N);
  }

  k_final<<<1, 64, 0, stream>>>(hsumP, W1, b1, W2, b2, out4, (float)N);
}

// Round 19
// 177.935 us; speedup vs baseline: 1.0565x; 1.0565x over previous
//
#include <hip/hip_runtime.h>
#include <math.h>

constexpr int H = 64;

typedef __attribute__((ext_vector_type(8))) short bf16x8;
typedef __attribute__((ext_vector_type(4))) float f32x4;
typedef unsigned long long u64;

__device__ inline unsigned short f2bf(float f) {
  union { float f; unsigned int u; } c; c.f = f;
  unsigned int u = c.u;
  return (unsigned short)((u + 0x7FFF + ((u >> 16) & 1)) >> 16);  // RNE
}
__device__ inline float bf2f(unsigned int s) {
  union { unsigned int u; float f; } c; c.u = s << 16;
  return c.f;
}
// fp8 e4m3 via HW cvt (encode+decode on same chip -> self-consistent format)
__device__ inline unsigned char f2fp8(float f) {
  return (unsigned char)(__builtin_amdgcn_cvt_pk_fp8_f32(f, f, 0, false) & 0xFF);
}

// ---- prep: zero hsumP+bcur2, transpose+bf16 weights (one kernel) ----
__global__ void k_prep(int* __restrict__ hist, float* __restrict__ hsumP,
                       int* __restrict__ bcur2,
                       const float* __restrict__ Wmsg, const float* __restrict__ Wupd,
                       unsigned short* __restrict__ WmT, unsigned short* __restrict__ WuT,
                       int n) {
  int t = blockIdx.x * blockDim.x + threadIdx.x;
  if (t < n) hist[t] = 0;
  if (t < 512) hsumP[t] = 0.f;
  if (t < 64) bcur2[t] = 0;
  int u = t - n;
  if (u >= 0 && u < 3 * 12288) {
    int l = u / 12288, rem = u % 12288;
    if (rem < 4096) {
      int j = rem >> 6, k = rem & 63;
      WmT[l * 4096 + rem] = f2bf(Wmsg[(size_t)l * 66 * 64 + k * 64 + j]);
    } else {
      int r2 = rem - 4096;
      int j = r2 >> 7, k = r2 & 127;
      WuT[l * 8192 + r2] = f2bf(Wupd[(size_t)l * 128 * 64 + k * 64 + j]);
    }
  }
}

// ---- fallback-path CSR build (N > 65536 only) ----
__global__ void k_hist(const int* __restrict__ dst, int* __restrict__ hist, int E) {
  int e = blockIdx.x * blockDim.x + threadIdx.x;
  if (e < E) atomicAdd(&hist[dst[e]], 1);
}

__global__ void k_scan1(const int* __restrict__ hist, int* __restrict__ bsum, int n) {
  __shared__ int sred[256];
  int tid = threadIdx.x;
  int base = blockIdx.x * 1024 + tid * 4;
  int s = 0;
#pragma unroll
  for (int k = 0; k < 4; ++k) { int i = base + k; if (i < n) s += hist[i]; }
  sred[tid] = s;
  __syncthreads();
  for (int d = 128; d > 0; d >>= 1) {
    if (tid < d) sred[tid] += sred[tid + d];
    __syncthreads();
  }
  if (tid == 0) bsum[blockIdx.x] = sred[0];
}

__global__ void k_scan2(int* __restrict__ bsum, int nb) {
  __shared__ int sd[1024];
  int tid = threadIdx.x;
  int v = (tid < nb) ? bsum[tid] : 0;
  sd[tid] = v;
  __syncthreads();
  for (int d = 1; d < 1024; d <<= 1) {
    int t = (tid >= d) ? sd[tid - d] : 0;
    __syncthreads();
    sd[tid] += t;
    __syncthreads();
  }
  if (tid < nb) bsum[tid] = sd[tid] - v;
}

__global__ void k_scan3(const int* __restrict__ hist, const int* __restrict__ bsum,
                        int* __restrict__ row_ptr, int* __restrict__ pos, int n) {
  __shared__ int sth[256];
  int tid = threadIdx.x;
  int base = blockIdx.x * 1024 + tid * 4;
  int v[4]; int s = 0;
#pragma unroll
  for (int k = 0; k < 4; ++k) { int i = base + k; v[k] = (i < n) ? hist[i] : 0; s += v[k]; }
  sth[tid] = s;
  __syncthreads();
  for (int d = 1; d < 256; d <<= 1) {
    int t = (tid >= d) ? sth[tid - d] : 0;
    __syncthreads();
    sth[tid] += t;
    __syncthreads();
  }
  int run = bsum[blockIdx.x] + sth[tid] - s;
  if (blockIdx.x == 0 && tid == 0) row_ptr[0] = 0;
#pragma unroll
  for (int k = 0; k < 4; ++k) {
    int i = base + k;
    if (i < n) {
      pos[i] = run;
      run += v[k];
      row_ptr[i + 1] = run;
    }
  }
}

__global__ void k_scatter(const int* __restrict__ src, const int* __restrict__ dst,
                          const float* __restrict__ ea, int* __restrict__ pos,
                          u64* __restrict__ erec, int E) {
  int e = blockIdx.x * blockDim.x + threadIdx.x;
  if (e < E) {
    int d = dst[e];
    int p = atomicAdd(&pos[d], 1);
    u64 lo = f2bf(ea[2 * e]);
    u64 hi = f2bf(ea[2 * e + 1]);
    erec[p] = (u64)(unsigned int)src[e] | ((lo | (hi << 16)) << 32);
  }
}

// ---- k_part: block-local bucket sort (2048 edges/block); NO global hist ----
__global__ void k_part(const int* __restrict__ src, const int* __restrict__ dst,
                       const float2* __restrict__ ea2,
                       int* __restrict__ bcur2,
                       u64* __restrict__ staged, int E, int B, int C) {
  __shared__ u64 srt[2048];                   // 16 KB
  __shared__ int cnt[64], offs[64], gbase[64];
  int tid = threadIdx.x;
  int base = blockIdx.x * 2048;
  if (tid < 64) cnt[tid] = 0;
  __syncthreads();
  u64 rec_[8]; int bk_[8], rk_[8];
#pragma unroll
  for (int k = 0; k < 8; ++k) {
    int e = base + k * 256 + tid;
    if (e < E) {
      int d = dst[e];
      int bk = d >> 10;
      float2 eav = ea2[e];
      unsigned int eap = (unsigned int)f2bf(eav.x) | ((unsigned int)f2bf(eav.y) << 16);
      rec_[k] = (u64)(unsigned int)(src[e] & 0xFFFF)
              | ((u64)(unsigned int)(d & 1023) << 16)
              | ((u64)(unsigned int)bk << 26)
              | ((u64)eap << 32);
      bk_[k] = bk;
      rk_[k] = atomicAdd(&cnt[bk], 1);
    } else bk_[k] = -1;
  }
  __syncthreads();
  if (tid == 0) {
    int run = 0;
    for (int b = 0; b < B; ++b) { offs[b] = run; run += cnt[b]; }
  }
  __syncthreads();
#pragma unroll
  for (int k = 0; k < 8; ++k)
    if (bk_[k] >= 0) srt[offs[bk_[k]] + rk_[k]] = rec_[k];
  __syncthreads();
  if (tid < B && cnt[tid] > 0) gbase[tid] = atomicAdd(&bcur2[tid], cnt[tid]);
  __syncthreads();
  int total = (base + 2048 <= E) ? 2048 : (E > base ? E - base : 0);
  for (int i = tid; i < total; i += 256) {
    u64 r = srt[i];
    int bk = (int)((r >> 26) & 63u);
    staged[(size_t)bk * C + gbase[bk] + (i - offs[bk])] = r;  // full-line appends
  }
}

// ---- k_place: per-bucket histogram + scan -> row_ptr; then place records ----
__global__ void k_place(const u64* __restrict__ staged, const int* __restrict__ bcur2,
                        int* __restrict__ row_ptr, u64* __restrict__ erec,
                        int N_, int C, int B) {
  __shared__ int cnt2[1024];
  __shared__ int rloc[1024];
  __shared__ int sbase;
  int b = blockIdx.x;
  int nd0 = b << 10;
  int nn = min(nd0 + 1024, N_) - nd0;
  int tid = threadIdx.x;  // 1024 threads
  cnt2[tid] = 0;
  if (tid == 0) {
    int s = 0;
    for (int i = 0; i < b; ++i) s += bcur2[i];
    sbase = s;
  }
  __syncthreads();
  int count = bcur2[b];
  const u64* sb = staged + (size_t)b * C;
  for (int i = tid; i < count; i += 1024) {
    int dl = (int)((sb[i] >> 16) & 1023u);
    atomicAdd(&cnt2[dl], 1);
  }
  __syncthreads();
  int v = cnt2[tid];
  rloc[tid] = v;
  __syncthreads();
  for (int d = 1; d < 1024; d <<= 1) {
    int t = (tid >= d) ? rloc[tid - d] : 0;
    __syncthreads();
    rloc[tid] += t;
    __syncthreads();
  }
  int myrp = sbase + rloc[tid] - v;
  __syncthreads();
  rloc[tid] = myrp;
  cnt2[tid] = 0;
  if (tid < nn) row_ptr[nd0 + tid] = myrp;
  if (b == B - 1 && tid == 0) row_ptr[N_] = sbase + count;
  __syncthreads();
  for (int i = tid; i < count; i += 1024) {
    u64 r = sb[i];
    int dl = (int)((r >> 16) & 1023u);
    int p = rloc[dl] + atomicAdd(&cnt2[dl], 1);
    erec[p] = (r & 0xFFFFull) | ((r >> 32) << 32);
  }
}

// ---- fused input projection + gemm0 ----
__global__ void k_inproj_gemm(const float* __restrict__ x, const float* __restrict__ Win,
                              const float* __restrict__ bin,
                              const unsigned short* __restrict__ wmt,
                              unsigned short* __restrict__ hb,
                              unsigned char* __restrict__ g, int n) {
  int lane = threadIdx.x & 63;
  int wv = blockIdx.x * (blockDim.x >> 6) + (threadIdx.x >> 6);
  int v0 = wv * 16;
  if (v0 >= n) return;
  int r16 = lane & 15, hi = lane >> 4;
  int row = v0 + r16;
  float x0 = 0.f, x1 = 0.f;
  if (row < n) { x0 = x[2 * row]; x1 = x[2 * row + 1]; }
  union { bf16x8 v; unsigned short u[8]; } af[2];
#pragma unroll
  for (int s = 0; s < 2; ++s)
#pragma unroll
    for (int t = 0; t < 8; ++t) {
      int j = s * 32 + hi * 8 + t;
      af[s].u[t] = f2bf(fmaf(x0, Win[j], fmaf(x1, Win[64 + j], bin[j])));
    }
  if (row < n) {
    *(bf16x8*)(hb + (size_t)row * H + hi * 8)      = af[0].v;
    *(bf16x8*)(hb + (size_t)row * H + 32 + hi * 8) = af[1].v;
  }
  bf16x8 bfr[2][4];
#pragma unroll
  for (int ks = 0; ks < 2; ++ks)
#pragma unroll
    for (int jt = 0; jt < 4; ++jt)
      bfr[ks][jt] = *(const bf16x8*)(wmt + (jt * 16 + r16) * 64 + ks * 32 + hi * 8);
  f32x4 acc[4] = {};
#pragma unroll
  for (int ks = 0; ks < 2; ++ks)
#pragma unroll
    for (int jt = 0; jt < 4; ++jt)
      acc[jt] = __builtin_amdgcn_mfma_f32_16x16x32_bf16(af[ks].v, bfr[ks][jt], acc[jt], 0, 0, 0);
#pragma unroll
  for (int jt = 0; jt < 4; ++jt) {
    int col = jt * 16 + r16;
#pragma unroll
    for (int r = 0; r < 4; ++r) {
      int orow = v0 + hi * 4 + r;
      if (orow < n) g[(size_t)orow * H + col] = f2fp8(acc[jt][r]);
    }
  }
}

// ---- per-chain accumulate: 8 fp8 feats from a uint2 ----
__device__ inline void acc8(float* a, uint2 gw, float e0, float e1,
                            const float4 waL, const float4 waH,
                            const float4 wbL, const float4 wbH,
                            const float4 bL, const float4 bH) {
  a[0] += fmaxf(fmaf(e0, waL.x, fmaf(e1, wbL.x, __builtin_amdgcn_cvt_f32_fp8(gw.x, 0) + bL.x)), 0.f);
  a[1] += fmaxf(fmaf(e0, waL.y, fmaf(e1, wbL.y, __builtin_amdgcn_cvt_f32_fp8(gw.x, 1) + bL.y)), 0.f);
  a[2] += fmaxf(fmaf(e0, waL.z, fmaf(e1, wbL.z, __builtin_amdgcn_cvt_f32_fp8(gw.x, 2) + bL.z)), 0.f);
  a[3] += fmaxf(fmaf(e0, waL.w, fmaf(e1, wbL.w, __builtin_amdgcn_cvt_f32_fp8(gw.x, 3) + bL.w)), 0.f);
  a[4] += fmaxf(fmaf(e0, waH.x, fmaf(e1, wbH.x, __builtin_amdgcn_cvt_f32_fp8(gw.y, 0) + bH.x)), 0.f);
  a[5] += fmaxf(fmaf(e0, waH.y, fmaf(e1, wbH.y, __builtin_amdgcn_cvt_f32_fp8(gw.y, 1) + bH.y)), 0.f);
  a[6] += fmaxf(fmaf(e0, waH.z, fmaf(e1, wbH.z, __builtin_amdgcn_cvt_f32_fp8(gw.y, 2) + bH.z)), 0.f);
  a[7] += fmaxf(fmaf(e0, waH.w, fmaf(e1, wbH.w, __builtin_amdgcn_cvt_f32_fp8(gw.y, 3) + bH.w)), 0.f);
}

// ---- fused layer: 32 nodes/block (1 node per 8-lane group); 4-wide chains ----
__global__ void k_layer(const unsigned char* __restrict__ g_in,
                        const int* __restrict__ row_ptr, const u64* __restrict__ erec,
                        const float* __restrict__ Wm2, const float* __restrict__ bm,
                        unsigned short* __restrict__ hb,
                        const unsigned short* __restrict__ wut,
                        const float* __restrict__ bu,
                        const unsigned short* __restrict__ wmt_next, // null on last layer
                        unsigned char* __restrict__ g_out,
                        float* __restrict__ hout,                    // non-null on last layer
                        const float* __restrict__ Wn, const float* __restrict__ bn,
                        float* __restrict__ probs, float* __restrict__ hsumP,
                        int n) {
  __shared__ __align__(16) unsigned short aggL[32][72];
  __shared__ __align__(16) unsigned short hstage[2][16][72];
  __shared__ float shsum[64];
  int v0 = blockIdx.x * 32;

  // ---- phase 1: 32 groups aggregate 32 nodes into aggL ----
  {
    int gid = threadIdx.x >> 3, r = threadIdx.x & 7;
    int j0 = r * 8;
    float4 waL = *(const float4*)(Wm2 + j0);
    float4 waH = *(const float4*)(Wm2 + j0 + 4);
    float4 wbL = *(const float4*)(Wm2 + 64 + j0);
    float4 wbH = *(const float4*)(Wm2 + 64 + j0 + 4);
    float4 bL  = *(const float4*)(bm + j0);
    float4 bH  = *(const float4*)(bm + j0 + 4);
    int v = v0 + gid;
    uint4 o = make_uint4(0, 0, 0, 0);
    if (v < n) {
      int beg = row_ptr[v], end = row_ptr[v + 1];
      float a[8] = {0.f, 0.f, 0.f, 0.f, 0.f, 0.f, 0.f, 0.f};
      int i = beg;
      for (; i + 3 < end; i += 4) {  // 4 independent gather chains
        u64 rA = erec[i], rB = erec[i + 1], rC = erec[i + 2], rD = erec[i + 3];
        uint2 gwA = *(const uint2*)(g_in + (size_t)(unsigned int)rA * H + j0);
        uint2 gwB = *(const uint2*)(g_in + (size_t)(unsigned int)rB * H + j0);
        uint2 gwC = *(const uint2*)(g_in + (size_t)(unsigned int)rC * H + j0);
        uint2 gwD = *(const uint2*)(g_in + (size_t)(unsigned int)rD * H + j0);
        unsigned int eA = (unsigned int)(rA >> 32), eB = (unsigned int)(rB >> 32);
        unsigned int eC = (unsigned int)(rC >> 32), eD = (unsigned int)(rD >> 32);
        acc8(a, gwA, bf2f(eA & 0xffffu), bf2f(eA >> 16), waL, waH, wbL, wbH, bL, bH);
        acc8(a, gwB, bf2f(eB & 0xffffu), bf2f(eB >> 16), waL, waH, wbL, wbH, bL, bH);
        acc8(a, gwC, bf2f(eC & 0xffffu), bf2f(eC >> 16), waL, waH, wbL, wbH, bL, bH);
        acc8(a, gwD, bf2f(eD & 0xffffu), bf2f(eD >> 16), waL, waH, wbL, wbH, bL, bH);
      }
      for (; i < end; ++i) {
        u64 rA = erec[i];
        uint2 gwA = *(const uint2*)(g_in + (size_t)(unsigned int)rA * H + j0);
        unsigned int eA = (unsigned int)(rA >> 32);
        acc8(a, gwA, bf2f(eA & 0xffffu), bf2f(eA >> 16), waL, waH, wbL, wbH, bL, bH);
      }
      float inv = 1.f / fmaxf((float)(end - beg), 1.f);
      o.x = (unsigned int)f2bf(a[0] * inv) | ((unsigned int)f2bf(a[1] * inv) << 16);
      o.y = (unsigned int)f2bf(a[2] * inv) | ((unsigned int)f2bf(a[3] * inv) << 16);
      o.z = (unsigned int)f2bf(a[4] * inv) | ((unsigned int)f2bf(a[5] * inv) << 16);
      o.w = (unsigned int)f2bf(a[6] * inv) | ((unsigned int)f2bf(a[7] * inv) << 16);
    }
    *(uint4*)(&aggL[gid][j0]) = o;
  }
  __syncthreads();

  // ---- phase 2: waves 0,1 do the update MFMA for rows v0..v0+31 ----
  int lane = threadIdx.x & 63;
  int w = threadIdx.x >> 6;
  bool mw = (w < 2);
  int wv0 = v0 + w * 16;
  bool act = mw && (wv0 < n);
  int r16 = lane & 15, hi = lane >> 4;
  if (hout && threadIdx.x < 64) shsum[threadIdx.x] = 0.f;
  bf16x8 bfr[4][4];
#pragma unroll
  for (int ks = 0; ks < 4; ++ks)
#pragma unroll
    for (int jt = 0; jt < 4; ++jt)
      bfr[ks][jt] = *(const bf16x8*)(wut + (jt * 16 + r16) * 128 + ks * 32 + hi * 8);
  f32x4 acc[4];
#pragma unroll
  for (int jt = 0; jt < 4; ++jt) {
    float b = bu[jt * 16 + r16];
    acc[jt] = (f32x4){b, b, b, b};
  }
  bf16x8 afr[4];
  int row = wv0 + r16;
  if (act && row < n) {
    const unsigned short* hrow = hb + (size_t)row * H + hi * 8;
    afr[0] = *(const bf16x8*)(hrow);
    afr[1] = *(const bf16x8*)(hrow + 32);
  } else {
    afr[0] = afr[1] = (bf16x8){0,0,0,0,0,0,0,0};
  }
  if (mw) {
    int lw = w * 16 + r16;
    afr[2] = *(const bf16x8*)(&aggL[lw][hi * 8]);
    afr[3] = *(const bf16x8*)(&aggL[lw][32 + hi * 8]);
  } else {
    afr[2] = afr[3] = (bf16x8){0,0,0,0,0,0,0,0};
  }
#pragma unroll
  for (int ks = 0; ks < 4; ++ks)
#pragma unroll
    for (int jt = 0; jt < 4; ++jt)
      acc[jt] = __builtin_amdgcn_mfma_f32_16x16x32_bf16(afr[ks], bfr[ks][jt], acc[jt], 0, 0, 0);
  float ov[4][4];
  unsigned short ob[4][4];
#pragma unroll
  for (int jt = 0; jt < 4; ++jt) {
    int col = jt * 16 + r16;
#pragma unroll
    for (int r = 0; r < 4; ++r) {
      int orow = wv0 + hi * 4 + r;
      bool ok = act && orow < n;
      float o = fmaxf(acc[jt][r], 0.f);
      ov[jt][r] = ok ? o : 0.f;
      ob[jt][r] = f2bf(ov[jt][r]);
      if (ok) {
        hb[(size_t)orow * H + col] = ob[jt][r];
        if (hout) hout[(size_t)orow * H + col] = o;
      }
    }
  }
  if (wmt_next) {
    if (mw) {
#pragma unroll
      for (int jt = 0; jt < 4; ++jt)
#pragma unroll
        for (int r = 0; r < 4; ++r)
          hstage[w][hi * 4 + r][jt * 16 + r16] = ob[jt][r];
    }
    __syncthreads();
    if (mw) {
      bf16x8 af2[2];
      af2[0] = *(const bf16x8*)(&hstage[w][r16][hi * 8]);
      af2[1] = *(const bf16x8*)(&hstage[w][r16][32 + hi * 8]);
      bf16x8 bf2r[2][4];
#pragma unroll
      for (int ks = 0; ks < 2; ++ks)
#pragma unroll
        for (int jt = 0; jt < 4; ++jt)
          bf2r[ks][jt] = *(const bf16x8*)(wmt_next + (jt * 16 + r16) * 64 + ks * 32 + hi * 8);
      f32x4 acc2[4] = {};
#pragma unroll
      for (int ks = 0; ks < 2; ++ks)
#pragma unroll
        for (int jt = 0; jt < 4; ++jt)
          acc2[jt] = __builtin_amdgcn_mfma_f32_16x16x32_bf16(af2[ks], bf2r[ks][jt], acc2[jt], 0, 0, 0);
#pragma unroll
      for (int jt = 0; jt < 4; ++jt) {
        int col = jt * 16 + r16;
#pragma unroll
        for (int r = 0; r < 4; ++r) {
          int orow = wv0 + hi * 4 + r;
          if (act && orow < n) g_out[(size_t)orow * H + col] = f2fp8(acc2[jt][r]);
        }
      }
    }
  } else {
    float bn0 = bn[0];
    float lg[4] = {0.f, 0.f, 0.f, 0.f};
#pragma unroll
    for (int jt = 0; jt < 4; ++jt) {
      float wn = Wn[jt * 16 + r16];
#pragma unroll
      for (int r = 0; r < 4; ++r) lg[r] = fmaf(ov[jt][r], wn, lg[r]);
    }
#pragma unroll
    for (int d = 1; d < 16; d <<= 1) {
#pragma unroll
      for (int r = 0; r < 4; ++r) lg[r] += __shfl_xor(lg[r], d);
    }
    if (r16 == 0 && act) {
#pragma unroll
      for (int r = 0; r < 4; ++r) {
        int orow = wv0 + hi * 4 + r;
        if (orow < n) probs[orow] = 1.f / (1.f + expf(-(lg[r] + bn0)));
      }
    }
    __syncthreads();
#pragma unroll
    for (int jt = 0; jt < 4; ++jt) {
      float s = ov[jt][0] + ov[jt][1] + ov[jt][2] + ov[jt][3];
      s += __shfl_xor(s, 16); s += __shfl_xor(s, 32);
      if (hi == 0) atomicAdd(&shsum[jt * 16 + r16], s);
    }
    __syncthreads();
    if (threadIdx.x < 64)
      atomicAdd(&hsumP[((blockIdx.x & 7) << 6) + threadIdx.x], shsum[threadIdx.x]);
  }
}

// ---- global mean + 2-layer head (tiny) ----
__global__ void k_final(const float* __restrict__ hsumP,
                        const float* __restrict__ W1, const float* __restrict__ b1,
                        const float* __restrict__ W2, const float* __restrict__ b2,
                        float* __restrict__ out4, float n_nodes) {
  __shared__ float hmean[64];
  __shared__ float z1[32];
  int tid = threadIdx.x;
  if (tid < 64) {
    float s = 0.f;
#pragma unroll
    for (int b = 0; b < 8; ++b) s += hsumP[b * 64 + tid];
    hmean[tid] = s / n_nodes;
  }
  __syncthreads();
  if (tid < 32) {
    float a = b1[tid];
    for (int k = 0; k < 64; ++k) a = fmaf(hmean[k], W1[k * 32 + tid], a);
    z1[tid] = fmaxf(a, 0.f);
  }
  __syncthreads();
  if (tid < 4) {
    float a = b2[tid];
    for (int k = 0; k < 32; ++k) a = fmaf(z1[k], W2[k * 4 + tid], a);
    out4[tid] = a;
  }
}

extern "C" void kernel_launch(void* const* d_in, const int* in_sizes, int n_in,
                              void* d_out, int out_size, void* d_ws, size_t ws_size,
                              hipStream_t stream) {
  const float* x    = (const float*)d_in[0];
  const int*   ei   = (const int*)d_in[1];
  const float* ea   = (const float*)d_in[2];
  const float* Win  = (const float*)d_in[3];
  const float* bin  = (const float*)d_in[4];
  const float* Wmsg = (const float*)d_in[5];
  const float* bmsg = (const float*)d_in[6];
  const float* Wupd = (const float*)d_in[7];
  const float* bupd = (const float*)d_in[8];
  const float* Wn   = (const float*)d_in[9];
  const float* bn   = (const float*)d_in[10];
  const float* W1   = (const float*)d_in[13];
  const float* b1   = (const float*)d_in[14];
  const float* W2   = (const float*)d_in[15];
  const float* b2   = (const float*)d_in[16];

  const int N = in_sizes[0] / 2;
  const int E = in_sizes[1] / 2;
  const int* src = ei;
  const int* dst = ei + E;

  const int B = (N + 1023) >> 10;            // dst-buckets of 1024 nodes
  const int C = (2 * (E / (B > 0 ? B : 1)) + 2048 + 255) & ~255;  // per-bucket staging cap

  char* ws = (char*)d_ws;
  size_t off = 0;
  auto alloc = [&](size_t bytes) {
    void* p = ws + off;
    off = (off + bytes + 255) & ~(size_t)255;
    return p;
  };
  int*   hist  = (int*)  alloc((size_t)N * 4);
  int*   rptr  = (int*)  alloc((size_t)(N + 1) * 4);
  int*   pos   = (int*)  alloc((size_t)N * 4);
  int*   bsum  = (int*)  alloc((size_t)1024 * 4);
  int*   bcur2 = (int*)  alloc((size_t)64 * 4);
  u64*   staged = (u64*) alloc((size_t)(B <= 64 ? 64 : 0) * C * 8 + 8);
  u64*   erec  = (u64*)  alloc((size_t)E * 8);
  unsigned short* hb   = (unsigned short*)alloc((size_t)N * H * 2);
  unsigned char*  gA   = (unsigned char*) alloc((size_t)N * H);   // fp8 ping
  unsigned char*  gB   = (unsigned char*) alloc((size_t)N * H);   // fp8 pong
  unsigned short* WmT  = (unsigned short*)alloc((size_t)3 * 64 * 64 * 2);
  unsigned short* WuT  = (unsigned short*)alloc((size_t)3 * 64 * 128 * 2);
  float* hsumP = (float*)alloc(8 * 64 * 4);
  (void)ws_size;

  float* probs = (float*)d_out;          // [N]
  float* out4  = probs + N;              // [4]
  float* h     = out4 + 4;               // [N, 64] fp32 final embeddings

  int eb = (E + 255) / 256;
  int sb = (N + 1023) / 1024;
  k_prep<<<(N + 3 * 12288 + 255) / 256, 256, 0, stream>>>(hist, hsumP, bcur2,
                                                          Wmsg, Wupd, WmT, WuT, N);
  if (B <= 64) {
    k_part<<<(E + 2047) / 2048, 256, 0, stream>>>(src, dst, (const float2*)ea,
                                                  bcur2, staged, E, B, C);
    k_place<<<B, 1024, 0, stream>>>(staged, bcur2, rptr, erec, N, C, B);
  } else {
    k_hist<<<eb, 256, 0, stream>>>(dst, hist, E);
    k_scan1<<<sb, 256, 0, stream>>>(hist, bsum, N);
    k_scan2<<<1, 1024, 0, stream>>>(bsum, sb);
    k_scan3<<<sb, 256, 0, stream>>>(hist, bsum, rptr, pos, N);
    k_scatter<<<eb, 256, 0, stream>>>(src, dst, ea, pos, erec, E);
  }

  int tiles = (N + 15) / 16;
  int mb = (tiles + 3) / 4;
  k_inproj_gemm<<<mb, 256, 0, stream>>>(x, Win, bin, WmT, hb, gA, N);

  int lb = (N + 31) / 32;     // fused layer: 32 nodes/block, 1 node per 8-lane group
  for (int l = 0; l < 3; ++l) {
    const unsigned char* gin = (l & 1) ? gB : gA;
    unsigned char* gout      = (l & 1) ? gA : gB;
    k_layer<<<lb, 256, 0, stream>>>(gin, rptr, erec,
                                    Wmsg + (size_t)l * 66 * 64 + 64 * 64,
                                    bmsg + (size_t)l * 64,
                                    hb, WuT + (size_t)l * 64 * 128,
                                    bupd + (size_t)l * 64,
                                    (l < 2) ? (WmT + (size_t)(l + 1) * 64 * 64) : nullptr,
                                    gout,
                                    (l == 2) ? h : nullptr,
                                    Wn, bn, probs, hsumP, N);
  }

  k_final<<<1, 64, 0, stream>>>(hsumP, W1, b1, W2, b2, out4, (float)N);
}